// Round 3
// baseline (2128.636 us; speedup 1.0000x reference)
//
#include <hip/hip_runtime.h>

#define N_NODES 100000
#define D_FEAT  64
#define N_EDGES 3200000
#define GAMMA   0.5f

#define BSHIFT   7                                      // 128 nodes per bucket
#define BNODES   (1 << BSHIFT)
#define BMASK    (BNODES - 1)
#define NB       ((N_NODES + BNODES - 1) >> BSHIFT)     // 782 buckets
#define HIST_EPB 16384                                  // edges per hist block
#define HIST_BLOCKS ((N_EDGES + HIST_EPB - 1) / HIST_EPB)  // 196

// K1: per-block LDS histogram of dst-buckets (few global atomics),
// fused: zero the edge part of the output.
__global__ void hist_zero_kernel(const int* __restrict__ dst,
                                 int* __restrict__ counts,
                                 float* __restrict__ out_edge) {
    __shared__ int lcnt[NB];
    for (int i = threadIdx.x; i < NB; i += blockDim.x) lcnt[i] = 0;
    __syncthreads();
    int base = blockIdx.x * HIST_EPB;
    int end  = base + HIST_EPB; if (end > N_EDGES) end = N_EDGES;
    for (int i = base + threadIdx.x; i < end; i += blockDim.x) {
        __hip_atomic_fetch_add(&lcnt[dst[i] >> BSHIFT], 1,
                               __ATOMIC_RELAXED, __HIP_MEMORY_SCOPE_WORKGROUP);
        out_edge[i] = 0.0f;
    }
    __syncthreads();
    for (int i = threadIdx.x; i < NB; i += blockDim.x) {
        int c = lcnt[i];
        if (c) atomicAdd(&counts[i], c);
    }
}

// K2: single-block scan over 782 bucket counts -> offs[NB+1], curs[NB]
__global__ void scan_kernel(const int* __restrict__ counts,
                            int* __restrict__ offs,
                            int* __restrict__ curs) {
    __shared__ int buf[NB];
    int tid = threadIdx.x;
    if (tid < NB) buf[tid] = counts[tid];
    __syncthreads();
    for (int off = 1; off < NB; off <<= 1) {
        int v = 0;
        if (tid < NB && tid >= off) v = buf[tid - off];
        __syncthreads();
        if (tid < NB) buf[tid] += v;
        __syncthreads();
    }
    if (tid < NB) {
        int inc = buf[tid];
        int exc = inc - counts[tid];
        offs[tid] = exc;
        curs[tid] = exc;
        if (tid == NB - 1) offs[NB] = inc;   // == N_EDGES
    }
}

// K3: bin edges by dst-bucket. rec = (src | dlocal<<17, e)
__global__ void scatter_kernel(const int* __restrict__ src,
                               const int* __restrict__ dst,
                               const float* __restrict__ e,
                               int* __restrict__ curs,
                               uint2* __restrict__ recs) {
    int i = blockIdx.x * blockDim.x + threadIdx.x;
    if (i >= N_EDGES) return;
    int t = dst[i];
    int b = t >> BSHIFT;
    int p = atomicAdd(&curs[b], 1);
    unsigned pk = (unsigned)src[i] | ((unsigned)(t & BMASK) << 17);
    recs[p] = make_uint2(pk, __float_as_uint(e[i]));
}

// K4: one block per bucket. Accumulate messages into a 32KB LDS tile with
// native LDS f32 atomics, then single coalesced write fused with -GAMMA*h0.
__global__ void __launch_bounds__(256)
accum_kernel(const float* __restrict__ h,
             const int* __restrict__ offs,
             const uint2* __restrict__ recs,
             float* __restrict__ out) {
    __shared__ float tile[BNODES * D_FEAT];   // 32 KB
    const int b   = blockIdx.x;
    const int tid = threadIdx.x;
    const int d   = tid & 63;
    const int wid = tid >> 6;

    for (int i = tid; i < BNODES * D_FEAT; i += 256) tile[i] = 0.0f;
    __syncthreads();

    const int lo  = offs[b], hi = offs[b + 1];
    const int cnt = hi - lo;
    const int per = (cnt + 3) >> 2;          // 4 waves per block
    int k   = lo + wid * per;
    int end = k + per; if (end > hi) end = hi;

    for (; k + 4 <= end; k += 4) {
        uint2 r0 = recs[k], r1 = recs[k+1], r2 = recs[k+2], r3 = recs[k+3];
        float v0 = h[(r0.x & 0x1FFFF) * D_FEAT + d] * __uint_as_float(r0.y);
        float v1 = h[(r1.x & 0x1FFFF) * D_FEAT + d] * __uint_as_float(r1.y);
        float v2 = h[(r2.x & 0x1FFFF) * D_FEAT + d] * __uint_as_float(r2.y);
        float v3 = h[(r3.x & 0x1FFFF) * D_FEAT + d] * __uint_as_float(r3.y);
        __hip_atomic_fetch_add(&tile[(r0.x >> 17) * D_FEAT + d], v0,
                               __ATOMIC_RELAXED, __HIP_MEMORY_SCOPE_WORKGROUP);
        __hip_atomic_fetch_add(&tile[(r1.x >> 17) * D_FEAT + d], v1,
                               __ATOMIC_RELAXED, __HIP_MEMORY_SCOPE_WORKGROUP);
        __hip_atomic_fetch_add(&tile[(r2.x >> 17) * D_FEAT + d], v2,
                               __ATOMIC_RELAXED, __HIP_MEMORY_SCOPE_WORKGROUP);
        __hip_atomic_fetch_add(&tile[(r3.x >> 17) * D_FEAT + d], v3,
                               __ATOMIC_RELAXED, __HIP_MEMORY_SCOPE_WORKGROUP);
    }
    for (; k < end; ++k) {
        uint2 r = recs[k];
        float v = h[(r.x & 0x1FFFF) * D_FEAT + d] * __uint_as_float(r.y);
        __hip_atomic_fetch_add(&tile[(r.x >> 17) * D_FEAT + d], v,
                               __ATOMIC_RELAXED, __HIP_MEMORY_SCOPE_WORKGROUP);
    }
    __syncthreads();

    const int nbase = b << BSHIFT;
    int nmax = N_NODES - nbase; if (nmax > BNODES) nmax = BNODES;
    const int total = nmax * D_FEAT;
    for (int i = tid; i < total; i += 256) {
        int g = nbase * D_FEAT + i;
        out[g] = tile[i] - GAMMA * h[g];
    }
}

// ---------------- fallback atomic path (if ws too small) ----------------

__global__ void init_out_kernel(const float* __restrict__ x,
                                float* __restrict__ out,
                                int nd, int total) {
    int i = blockIdx.x * blockDim.x + threadIdx.x;
    if (i < nd)         out[i] = -GAMMA * x[i];
    else if (i < total) out[i] = 0.0f;
}

__global__ void edge_scatter_kernel(const float* __restrict__ h,
                                    const float* __restrict__ e,
                                    const int* __restrict__ src,
                                    const int* __restrict__ dst,
                                    float* __restrict__ out) {
    long long idx = (long long)blockIdx.x * blockDim.x + threadIdx.x;
    int edge = (int)(idx >> 6);
    int d    = (int)(idx & 63);
    if (edge >= N_EDGES) return;
    atomicAdd(&out[dst[edge] * D_FEAT + d], h[src[edge] * D_FEAT + d] * e[edge]);
}

// ---------------- launch ----------------

extern "C" void kernel_launch(void* const* d_in, const int* in_sizes, int n_in,
                              void* d_out, int out_size, void* d_ws, size_t ws_size,
                              hipStream_t stream) {
    const float* x   = (const float*)d_in[1];
    const int*   src = (const int*)d_in[2];
    const int*   dst = (const int*)d_in[3];
    float*       out = (float*)d_out;

    const int nd = N_NODES * D_FEAT;

    // ws layout: counts[NB] | offs[NB+1] | curs[NB] | pad | recs[E] (uint2)
    size_t ints    = (size_t)NB * 3 + 1;
    size_t rec_off = (ints * 4 + 15) & ~(size_t)15;
    size_t needed  = rec_off + (size_t)N_EDGES * 8;

    if (ws_size >= needed) {
        int*   counts = (int*)d_ws;
        int*   offs   = counts + NB;
        int*   curs   = offs + NB + 1;
        uint2* recs   = (uint2*)((char*)d_ws + rec_off);

        hipMemsetAsync(counts, 0, NB * sizeof(int), stream);
        hist_zero_kernel<<<HIST_BLOCKS, 256, 0, stream>>>(dst, counts, out + nd);
        scan_kernel<<<1, 1024, 0, stream>>>(counts, offs, curs);
        scatter_kernel<<<(N_EDGES + 255) / 256, 256, 0, stream>>>(src, dst, x + nd, curs, recs);
        accum_kernel<<<NB, 256, 0, stream>>>(x, offs, recs, out);
    } else {
        const int total = nd + N_EDGES;
        init_out_kernel<<<(total + 255) / 256, 256, 0, stream>>>(x, out, nd, total);
        long long threads = (long long)N_EDGES * 64;
        edge_scatter_kernel<<<(int)((threads + 255) / 256), 256, 0, stream>>>(
            x, x + nd, src, dst, out);
    }
}

// Round 4
// 288.656 us; speedup vs baseline: 7.3743x; 7.3743x over previous
//
#include <hip/hip_runtime.h>

#define N_NODES 100000
#define D_FEAT  64
#define N_EDGES 3200000
#define GAMMA   0.5f

#define BSH   8                                   // 256 nodes per bucket
#define BN    (1 << BSH)
#define NB    ((N_NODES + BN - 1) >> BSH)         // 391 buckets
#define NBP   512                                 // pow2 pad for scans

#define H_BLOCKS 1024
#define H_EPB    ((N_EDGES + H_BLOCKS - 1) / H_BLOCKS)   // 3125

#define K1_CH    4096                             // edges per K1 block
#define K1_BLOCKS ((N_EDGES + K1_CH - 1) / K1_CH) // 782

#define K2_CAP   10240                            // max recs sortable in LDS

#define SRC_MASK 0x1FFFFu                         // 17 bits for src

// ---- K0a: bucket histogram (LDS-privatized) + zero edge part of out ----
__global__ void hist_zero_kernel(const int* __restrict__ dst,
                                 int* __restrict__ counts,
                                 float* __restrict__ out_edge) {
    __shared__ int lcnt[NB];
    for (int i = threadIdx.x; i < NB; i += blockDim.x) lcnt[i] = 0;
    __syncthreads();
    int base = blockIdx.x * H_EPB;
    int end  = base + H_EPB; if (end > N_EDGES) end = N_EDGES;
    for (int i = base + threadIdx.x; i < end; i += blockDim.x) {
        __hip_atomic_fetch_add(&lcnt[dst[i] >> BSH], 1,
                               __ATOMIC_RELAXED, __HIP_MEMORY_SCOPE_WORKGROUP);
        out_edge[i] = 0.0f;
    }
    __syncthreads();
    for (int i = threadIdx.x; i < NB; i += blockDim.x) {
        int c = lcnt[i];
        if (c) atomicAdd(&counts[i], c);
    }
}

// ---- K0b: scan 391 bucket counts -> offs/curs; init bflag, node_offs[N] ----
__global__ void scan_kernel(const int* __restrict__ counts,
                            int* __restrict__ offs,
                            int* __restrict__ curs,
                            int* __restrict__ bflag,
                            int* __restrict__ node_offs) {
    __shared__ int sb[NBP];
    int t = threadIdx.x;                          // 512 threads
    int c = (t < NB) ? counts[t] : 0;
    sb[t] = c;
    __syncthreads();
    for (int off = 1; off < NBP; off <<= 1) {
        int v = 0;
        if (t >= off) v = sb[t - off];
        __syncthreads();
        sb[t] += v;
        __syncthreads();
    }
    if (t < NB) {
        offs[t] = sb[t] - c;
        curs[t] = sb[t] - c;
        bflag[t] = 0;
    }
    if (t == NBP - 1) offs[NB] = sb[t];           // == N_EDGES
    if (t == 0) node_offs[N_NODES] = N_EDGES;
}

// ---- K1: chunk-local LDS sort by bucket, burst-copy to global bins ----
__global__ void __launch_bounds__(512)
bucket_scatter_kernel(const int* __restrict__ src,
                      const int* __restrict__ dst,
                      const float* __restrict__ e,
                      int* __restrict__ curs,
                      uint2* __restrict__ recs) {
    __shared__ uint2          stage[K1_CH];       // 32 KB
    __shared__ unsigned short bkt16[K1_CH];       // 8 KB
    __shared__ int hist[NB], ebuf[NB], cur[NB], gbase[NB];
    __shared__ int sb[NBP];

    const int t    = threadIdx.x;
    const int base = blockIdx.x * K1_CH;
    int chcnt = N_EDGES - base; if (chcnt > K1_CH) chcnt = K1_CH;

    for (int i = t; i < NB; i += 512) hist[i] = 0;
    __syncthreads();
    // pass 1: histogram
    for (int i = t; i < chcnt; i += 512) {
        int b = dst[base + i] >> BSH;
        __hip_atomic_fetch_add(&hist[b], 1,
                               __ATOMIC_RELAXED, __HIP_MEMORY_SCOPE_WORKGROUP);
    }
    __syncthreads();
    // scan NB (padded to 512)
    int c = (t < NB) ? hist[t] : 0;
    sb[t] = c;
    __syncthreads();
    for (int off = 1; off < NBP; off <<= 1) {
        int v = 0;
        if (t >= off) v = sb[t - off];
        __syncthreads();
        sb[t] += v;
        __syncthreads();
    }
    if (t < NB) {
        ebuf[t] = sb[t] - c;                      // chunk-local exclusive
        cur[t]  = 0;
        gbase[t] = c ? atomicAdd(&curs[t], c) : 0; // reserve global space
    }
    __syncthreads();
    // pass 2: scatter into LDS, bucket-sorted
    for (int i = t; i < chcnt; i += 512) {
        int gi = base + i;
        int dv = dst[gi];
        int b  = dv >> BSH;
        int p  = ebuf[b] + __hip_atomic_fetch_add(&cur[b], 1,
                        __ATOMIC_RELAXED, __HIP_MEMORY_SCOPE_WORKGROUP);
        unsigned pk = (unsigned)src[gi] | ((unsigned)(dv & (BN - 1)) << 17);
        stage[p] = make_uint2(pk, __float_as_uint(e[gi]));
        bkt16[p] = (unsigned short)b;
    }
    __syncthreads();
    // burst copy: consecutive LDS slots of a bucket -> consecutive global
    for (int i = t; i < chcnt; i += 512) {
        int b = bkt16[i];
        recs[gbase[b] + (i - ebuf[b])] = stage[i];
    }
}

// ---- K2: per-bucket node-level sort (in LDS, in place) + node_offs ----
__global__ void __launch_bounds__(512)
node_sort_kernel(const int* __restrict__ offs,
                 uint2* __restrict__ recs,
                 int* __restrict__ bflag,
                 int* __restrict__ node_offs) {
    __shared__ uint2 buf[K2_CAP];                 // 80 KB
    __shared__ int hist[BN], ebuf[BN], cur[BN];

    const int b  = blockIdx.x;
    const int t  = threadIdx.x;
    const int lo = offs[b];
    const int cnt = offs[b + 1] - lo;

    if (cnt > K2_CAP) {                           // overflow fallback (rare)
        if (t == 0) bflag[b] = 1;
        if (t < BN) {
            int g = (b << BSH) + t;
            if (g < N_NODES) node_offs[g] = lo;   // placeholder (unused by K3)
        }
        return;
    }

    for (int i = t; i < cnt; i += 512) buf[i] = recs[lo + i];
    if (t < BN) hist[t] = 0;
    __syncthreads();
    for (int i = t; i < cnt; i += 512) {
        int dl = buf[i].x >> 17;
        __hip_atomic_fetch_add(&hist[dl], 1,
                               __ATOMIC_RELAXED, __HIP_MEMORY_SCOPE_WORKGROUP);
    }
    __syncthreads();
    // scan BN=256 bins with 512 threads
    int c = 0;
    if (t < BN) { c = hist[t]; ebuf[t] = c; }
    __syncthreads();
    for (int off = 1; off < BN; off <<= 1) {
        int v = 0;
        if (t < BN && t >= off) v = ebuf[t - off];
        __syncthreads();
        if (t < BN) ebuf[t] += v;
        __syncthreads();
    }
    if (t < BN) {
        int exc = ebuf[t] - c;
        ebuf[t] = exc;
        cur[t]  = 0;
        int g = (b << BSH) + t;
        if (g < N_NODES) node_offs[g] = lo + exc;
    }
    __syncthreads();
    // scatter node-sorted back to global (in place; all reads done)
    for (int i = t; i < cnt; i += 512) {
        uint2 r = buf[i];
        int dl = r.x >> 17;
        int p  = lo + ebuf[dl] + __hip_atomic_fetch_add(&cur[dl], 1,
                        __ATOMIC_RELAXED, __HIP_MEMORY_SCOPE_WORKGROUP);
        recs[p] = r;
    }
}

// ---- K3: one wave per node, register accumulate, no atomics ----
__global__ void __launch_bounds__(512)
gather_kernel(const float* __restrict__ h,
              const int* __restrict__ offs,
              const int* __restrict__ node_offs,
              const int* __restrict__ bflag,
              const uint2* __restrict__ recs,
              float* __restrict__ out) {
    const int wid = threadIdx.x >> 6;
    const int d   = threadIdx.x & 63;
    const int n   = blockIdx.x * 8 + wid;
    if (n >= N_NODES) return;
    const int b = n >> BSH;

    float acc = 0.0f;
    if (!bflag[b]) {
        int lo = node_offs[n], hi = node_offs[n + 1];
        int k = lo;
        for (; k + 2 <= hi; k += 2) {             // unroll-2 for MLP
            uint2 r0 = recs[k], r1 = recs[k + 1];
            acc += h[(r0.x & SRC_MASK) * D_FEAT + d] * __uint_as_float(r0.y);
            acc += h[(r1.x & SRC_MASK) * D_FEAT + d] * __uint_as_float(r1.y);
        }
        if (k < hi) {
            uint2 r = recs[k];
            acc += h[(r.x & SRC_MASK) * D_FEAT + d] * __uint_as_float(r.y);
        }
    } else {                                      // unsorted bucket: scan-match
        int lo = offs[b], hi = offs[b + 1];
        unsigned dl = (unsigned)(n & (BN - 1));
        for (int k = lo; k < hi; ++k) {
            uint2 r = recs[k];
            if ((r.x >> 17) == dl)
                acc += h[(r.x & SRC_MASK) * D_FEAT + d] * __uint_as_float(r.y);
        }
    }
    int o = n * D_FEAT + d;
    out[o] = acc - GAMMA * h[o];
}

// ---------------- fallback atomic path (if ws too small) ----------------
__global__ void init_out_kernel(const float* __restrict__ x,
                                float* __restrict__ out,
                                int nd, int total) {
    int i = blockIdx.x * blockDim.x + threadIdx.x;
    if (i < nd)         out[i] = -GAMMA * x[i];
    else if (i < total) out[i] = 0.0f;
}

__global__ void edge_scatter_kernel(const float* __restrict__ h,
                                    const float* __restrict__ e,
                                    const int* __restrict__ src,
                                    const int* __restrict__ dst,
                                    float* __restrict__ out) {
    long long idx = (long long)blockIdx.x * blockDim.x + threadIdx.x;
    int edge = (int)(idx >> 6);
    int d    = (int)(idx & 63);
    if (edge >= N_EDGES) return;
    atomicAdd(&out[dst[edge] * D_FEAT + d], h[src[edge] * D_FEAT + d] * e[edge]);
}

// ---------------- launch ----------------
extern "C" void kernel_launch(void* const* d_in, const int* in_sizes, int n_in,
                              void* d_out, int out_size, void* d_ws, size_t ws_size,
                              hipStream_t stream) {
    const float* x   = (const float*)d_in[1];
    const int*   src = (const int*)d_in[2];
    const int*   dst = (const int*)d_in[3];
    float*       out = (float*)d_out;

    const int nd = N_NODES * D_FEAT;

    // ws: counts[NB] | offs[NB+1] | curs[NB] | bflag[NB] | node_offs[N+1] | recs[E]
    size_t ints    = (size_t)NB * 3 + 1 + NB + (size_t)N_NODES + 1;
    size_t rec_off = (ints * 4 + 15) & ~(size_t)15;
    size_t needed  = rec_off + (size_t)N_EDGES * 8;

    if (ws_size >= needed) {
        int*   counts    = (int*)d_ws;
        int*   offs      = counts + NB;
        int*   curs      = offs + NB + 1;
        int*   bflag     = curs + NB;
        int*   node_offs = bflag + NB;
        uint2* recs      = (uint2*)((char*)d_ws + rec_off);

        hipMemsetAsync(counts, 0, NB * sizeof(int), stream);
        hist_zero_kernel<<<H_BLOCKS, 256, 0, stream>>>(dst, counts, out + nd);
        scan_kernel<<<1, NBP, 0, stream>>>(counts, offs, curs, bflag, node_offs);
        bucket_scatter_kernel<<<K1_BLOCKS, 512, 0, stream>>>(src, dst, x + nd, curs, recs);
        node_sort_kernel<<<NB, 512, 0, stream>>>(offs, recs, bflag, node_offs);
        gather_kernel<<<(N_NODES + 7) / 8, 512, 0, stream>>>(
            x, offs, node_offs, bflag, recs, out);
    } else {
        const int total = nd + N_EDGES;
        init_out_kernel<<<(total + 255) / 256, 256, 0, stream>>>(x, out, nd, total);
        long long threads = (long long)N_EDGES * 64;
        edge_scatter_kernel<<<(int)((threads + 255) / 256), 256, 0, stream>>>(
            x, x + nd, src, dst, out);
    }
}

// Round 5
// 217.727 us; speedup vs baseline: 9.7767x; 1.3258x over previous
//
#include <hip/hip_runtime.h>

#define N_NODES 100000
#define D_FEAT  64
#define N_EDGES 3200000
#define GAMMA   0.5f

#define BSH   8                                   // 256 nodes per bucket
#define BN    (1 << BSH)
#define NB    ((N_NODES + BN - 1) >> BSH)         // 391 buckets
#define NBP   512                                 // pow2 pad for scans

#define H_BLOCKS 1024
#define H_EPB    ((N_EDGES + H_BLOCKS - 1) / H_BLOCKS)   // 3125

#define K1_CH    4096                             // edges per K1 block
#define K1_BLOCKS ((N_EDGES + K1_CH - 1) / K1_CH) // 782

#define K2_CAP   10240                            // max recs sortable in LDS

#define SRC_MASK 0x1FFFFu                         // 17 bits for src

// ---- K0a: bucket histogram (LDS-privatized) + zero edge part of out ----
__global__ void hist_zero_kernel(const int* __restrict__ dst,
                                 int* __restrict__ counts,
                                 float* __restrict__ out_edge) {
    __shared__ int lcnt[NB];
    for (int i = threadIdx.x; i < NB; i += blockDim.x) lcnt[i] = 0;
    __syncthreads();
    int base = blockIdx.x * H_EPB;
    int end  = base + H_EPB; if (end > N_EDGES) end = N_EDGES;
    for (int i = base + threadIdx.x; i < end; i += blockDim.x) {
        __hip_atomic_fetch_add(&lcnt[dst[i] >> BSH], 1,
                               __ATOMIC_RELAXED, __HIP_MEMORY_SCOPE_WORKGROUP);
        out_edge[i] = 0.0f;
    }
    __syncthreads();
    for (int i = threadIdx.x; i < NB; i += blockDim.x) {
        int c = lcnt[i];
        if (c) atomicAdd(&counts[i], c);
    }
}

// ---- K0b: scan 391 bucket counts -> offs/curs; init bflag, node_offs tail ----
__global__ void scan_kernel(const int* __restrict__ counts,
                            int* __restrict__ offs,
                            int* __restrict__ curs,
                            int* __restrict__ bflag,
                            int* __restrict__ node_offs) {
    __shared__ int sb[NBP];
    int t = threadIdx.x;                          // 512 threads
    int c = (t < NB) ? counts[t] : 0;
    sb[t] = c;
    __syncthreads();
    for (int off = 1; off < NBP; off <<= 1) {
        int v = 0;
        if (t >= off) v = sb[t - off];
        __syncthreads();
        sb[t] += v;
        __syncthreads();
    }
    if (t < NB) {
        offs[t] = sb[t] - c;
        curs[t] = sb[t] - c;
        bflag[t] = 0;
    }
    if (t == NBP - 1) offs[NB] = sb[t];           // == N_EDGES
    if (t == 0) node_offs[N_NODES] = N_EDGES;
}

// ---- K1: chunk-local LDS sort by bucket, burst-copy to global bins ----
__global__ void __launch_bounds__(512)
bucket_scatter_kernel(const int* __restrict__ src,
                      const int* __restrict__ dst,
                      const float* __restrict__ e,
                      int* __restrict__ curs,
                      uint2* __restrict__ recs) {
    __shared__ uint2          stage[K1_CH];       // 32 KB
    __shared__ unsigned short bkt16[K1_CH];       // 8 KB
    __shared__ int hist[NB], ebuf[NB], cur[NB], gbase[NB];
    __shared__ int sb[NBP];

    const int t    = threadIdx.x;
    const int base = blockIdx.x * K1_CH;
    int chcnt = N_EDGES - base; if (chcnt > K1_CH) chcnt = K1_CH;

    for (int i = t; i < NB; i += 512) hist[i] = 0;
    __syncthreads();
    for (int i = t; i < chcnt; i += 512) {
        int b = dst[base + i] >> BSH;
        __hip_atomic_fetch_add(&hist[b], 1,
                               __ATOMIC_RELAXED, __HIP_MEMORY_SCOPE_WORKGROUP);
    }
    __syncthreads();
    int c = (t < NB) ? hist[t] : 0;
    sb[t] = c;
    __syncthreads();
    for (int off = 1; off < NBP; off <<= 1) {
        int v = 0;
        if (t >= off) v = sb[t - off];
        __syncthreads();
        sb[t] += v;
        __syncthreads();
    }
    if (t < NB) {
        ebuf[t] = sb[t] - c;                      // chunk-local exclusive
        cur[t]  = 0;
        gbase[t] = c ? atomicAdd(&curs[t], c) : 0; // reserve global space
    }
    __syncthreads();
    for (int i = t; i < chcnt; i += 512) {
        int gi = base + i;
        int dv = dst[gi];
        int b  = dv >> BSH;
        int p  = ebuf[b] + __hip_atomic_fetch_add(&cur[b], 1,
                        __ATOMIC_RELAXED, __HIP_MEMORY_SCOPE_WORKGROUP);
        unsigned pk = (unsigned)src[gi] | ((unsigned)(dv & (BN - 1)) << 17);
        stage[p] = make_uint2(pk, __float_as_uint(e[gi]));
        bkt16[p] = (unsigned short)b;
    }
    __syncthreads();
    for (int i = t; i < chcnt; i += 512) {
        int b = bkt16[i];
        recs[gbase[b] + (i - ebuf[b])] = stage[i];
    }
}

// ---- K2: per-bucket node-level sort (in LDS, in place) + node_offs ----
__global__ void __launch_bounds__(512)
node_sort_kernel(const int* __restrict__ offs,
                 uint2* __restrict__ recs,
                 int* __restrict__ bflag,
                 int* __restrict__ node_offs) {
    __shared__ uint2 buf[K2_CAP];                 // 80 KB
    __shared__ int hist[BN], ebuf[BN], cur[BN];

    const int b  = blockIdx.x;
    const int t  = threadIdx.x;
    const int lo = offs[b];
    const int cnt = offs[b + 1] - lo;

    if (cnt > K2_CAP) {                           // overflow fallback (rare)
        if (t == 0) bflag[b] = 1;
        if (t < BN) {
            int g = (b << BSH) + t;
            if (g < N_NODES) node_offs[g] = lo;   // placeholder (unused by K3)
        }
        return;
    }

    for (int i = t; i < cnt; i += 512) buf[i] = recs[lo + i];
    if (t < BN) hist[t] = 0;
    __syncthreads();
    for (int i = t; i < cnt; i += 512) {
        int dl = buf[i].x >> 17;
        __hip_atomic_fetch_add(&hist[dl], 1,
                               __ATOMIC_RELAXED, __HIP_MEMORY_SCOPE_WORKGROUP);
    }
    __syncthreads();
    int c = 0;
    if (t < BN) { c = hist[t]; ebuf[t] = c; }
    __syncthreads();
    for (int off = 1; off < BN; off <<= 1) {
        int v = 0;
        if (t < BN && t >= off) v = ebuf[t - off];
        __syncthreads();
        if (t < BN) ebuf[t] += v;
        __syncthreads();
    }
    if (t < BN) {
        int exc = ebuf[t] - c;
        ebuf[t] = exc;
        cur[t]  = 0;
        int g = (b << BSH) + t;
        if (g < N_NODES) node_offs[g] = lo + exc;
    }
    __syncthreads();
    for (int i = t; i < cnt; i += 512) {
        uint2 r = buf[i];
        int dl = r.x >> 17;
        int p  = lo + ebuf[dl] + __hip_atomic_fetch_add(&cur[dl], 1,
                        __ATOMIC_RELAXED, __HIP_MEMORY_SCOPE_WORKGROUP);
        recs[p] = r;
    }
}

// ---- K3: one wave per node, 4 groups x 16 lanes, float4 gather ----
// group g handles edges lo+g, lo+g+4, ...; lane owns features [sub*4, sub*4+4)
__global__ void __launch_bounds__(512)
gather_kernel(const float* __restrict__ h,
              const int* __restrict__ offs,
              const int* __restrict__ node_offs,
              const int* __restrict__ bflag,
              const uint2* __restrict__ recs,
              float* __restrict__ out) {
    const int wid = threadIdx.x >> 6;
    const int n   = blockIdx.x * 8 + wid;
    if (n >= N_NODES) return;
    const int lane = threadIdx.x & 63;
    const int g    = lane >> 4;        // edge group 0..3
    const int sub  = lane & 15;        // float4 slot 0..15
    const int b    = n >> BSH;

    const float4* __restrict__ h4 = (const float4*)h;

    float ax = 0.f, ay = 0.f, az = 0.f, aw = 0.f;

    if (!bflag[b]) {
        const int lo = node_offs[n], hi = node_offs[n + 1];
        int kk = lo + g;
        uint2 r0 = (kk     < hi) ? recs[kk]     : make_uint2(0u, 0u);
        uint2 r1 = (kk + 4 < hi) ? recs[kk + 4] : make_uint2(0u, 0u);
        while (kk < hi) {
            uint2 c0 = r0, c1 = r1;
            kk += 8;
            r0 = (kk     < hi) ? recs[kk]     : make_uint2(0u, 0u);
            r1 = (kk + 4 < hi) ? recs[kk + 4] : make_uint2(0u, 0u);
            float4 v0 = h4[(c0.x & SRC_MASK) * 16 + sub];
            float4 v1 = h4[(c1.x & SRC_MASK) * 16 + sub];
            float  w0 = __uint_as_float(c0.y);
            float  w1 = __uint_as_float(c1.y);
            ax += v0.x * w0 + v1.x * w1;
            ay += v0.y * w0 + v1.y * w1;
            az += v0.z * w0 + v1.z * w1;
            aw += v0.w * w0 + v1.w * w1;
        }
    } else {                                      // unsorted bucket: scan-match
        const int lo = offs[b], hi = offs[b + 1];
        const unsigned dl = (unsigned)(n & (BN - 1));
        for (int k = lo + g; k < hi; k += 4) {
            uint2 r = recs[k];
            if ((r.x >> 17) == dl) {
                float4 v = h4[(r.x & SRC_MASK) * 16 + sub];
                float  w = __uint_as_float(r.y);
                ax += v.x * w; ay += v.y * w; az += v.z * w; aw += v.w * w;
            }
        }
    }

    // reduce across the 4 edge-groups (lanes with same sub)
    for (int m = 16; m <= 32; m <<= 1) {
        ax += __shfl_xor(ax, m);
        ay += __shfl_xor(ay, m);
        az += __shfl_xor(az, m);
        aw += __shfl_xor(aw, m);
    }

    if (g == 0) {
        const int o = n * 16 + sub;
        float4 h0 = h4[o];
        float4 r;
        r.x = ax - GAMMA * h0.x;
        r.y = ay - GAMMA * h0.y;
        r.z = az - GAMMA * h0.z;
        r.w = aw - GAMMA * h0.w;
        ((float4*)out)[o] = r;
    }
}

// ---------------- fallback atomic path (if ws too small) ----------------
__global__ void init_out_kernel(const float* __restrict__ x,
                                float* __restrict__ out,
                                int nd, int total) {
    int i = blockIdx.x * blockDim.x + threadIdx.x;
    if (i < nd)         out[i] = -GAMMA * x[i];
    else if (i < total) out[i] = 0.0f;
}

__global__ void edge_scatter_kernel(const float* __restrict__ h,
                                    const float* __restrict__ e,
                                    const int* __restrict__ src,
                                    const int* __restrict__ dst,
                                    float* __restrict__ out) {
    long long idx = (long long)blockIdx.x * blockDim.x + threadIdx.x;
    int edge = (int)(idx >> 6);
    int d    = (int)(idx & 63);
    if (edge >= N_EDGES) return;
    atomicAdd(&out[dst[edge] * D_FEAT + d], h[src[edge] * D_FEAT + d] * e[edge]);
}

// ---------------- launch ----------------
extern "C" void kernel_launch(void* const* d_in, const int* in_sizes, int n_in,
                              void* d_out, int out_size, void* d_ws, size_t ws_size,
                              hipStream_t stream) {
    const float* x   = (const float*)d_in[1];
    const int*   src = (const int*)d_in[2];
    const int*   dst = (const int*)d_in[3];
    float*       out = (float*)d_out;

    const int nd = N_NODES * D_FEAT;

    // ws: counts[NB] | offs[NB+1] | curs[NB] | bflag[NB] | node_offs[N+1] | recs[E]
    size_t ints    = (size_t)NB * 3 + 1 + NB + (size_t)N_NODES + 1;
    size_t rec_off = (ints * 4 + 15) & ~(size_t)15;
    size_t needed  = rec_off + (size_t)N_EDGES * 8;

    if (ws_size >= needed) {
        int*   counts    = (int*)d_ws;
        int*   offs      = counts + NB;
        int*   curs      = offs + NB + 1;
        int*   bflag     = curs + NB;
        int*   node_offs = bflag + NB;
        uint2* recs      = (uint2*)((char*)d_ws + rec_off);

        hipMemsetAsync(counts, 0, NB * sizeof(int), stream);
        hist_zero_kernel<<<H_BLOCKS, 256, 0, stream>>>(dst, counts, out + nd);
        scan_kernel<<<1, NBP, 0, stream>>>(counts, offs, curs, bflag, node_offs);
        bucket_scatter_kernel<<<K1_BLOCKS, 512, 0, stream>>>(src, dst, x + nd, curs, recs);
        node_sort_kernel<<<NB, 512, 0, stream>>>(offs, recs, bflag, node_offs);
        gather_kernel<<<(N_NODES + 7) / 8, 512, 0, stream>>>(
            x, offs, node_offs, bflag, recs, out);
    } else {
        const int total = nd + N_EDGES;
        init_out_kernel<<<(total + 255) / 256, 256, 0, stream>>>(x, out, nd, total);
        long long threads = (long long)N_EDGES * 64;
        edge_scatter_kernel<<<(int)((threads + 255) / 256), 256, 0, stream>>>(
            x, x + nd, src, dst, out);
    }
}

// Round 6
// 183.622 us; speedup vs baseline: 11.5925x; 1.1857x over previous
//
#include <hip/hip_runtime.h>

#define N_NODES 100000
#define D_FEAT  64
#define N_EDGES 3200000
#define GAMMA   0.5f

#define BSH   8                                   // 256 nodes per bucket
#define BN    (1 << BSH)
#define NB    ((N_NODES + BN - 1) >> BSH)         // 391 buckets
#define NBP   512                                 // pow2 pad for scans

#define H_BLOCKS 1024
#define H_EPB    ((N_EDGES + H_BLOCKS - 1) / H_BLOCKS)   // 3125

#define K1_CH    4096                             // edges per K1 block
#define K1_BLOCKS ((N_EDGES + K1_CH - 1) / K1_CH) // 782

#define K2_CAP   10240                            // max recs sortable in LDS

#define SRC_MASK 0x1FFFFu                         // 17 bits for src

// ---- K-1: h (f32) -> h16 (bf16, RNE) ----
__global__ void cvt_kernel(const float* __restrict__ h,
                           unsigned short* __restrict__ h16) {
    int i = blockIdx.x * blockDim.x + threadIdx.x;   // one float4
    if (i * 4 >= N_NODES * D_FEAT) return;
    float4 v = ((const float4*)h)[i];
    ushort4 o;
    unsigned u;
    u = __float_as_uint(v.x); o.x = (unsigned short)((u + 0x7fffu + ((u >> 16) & 1u)) >> 16);
    u = __float_as_uint(v.y); o.y = (unsigned short)((u + 0x7fffu + ((u >> 16) & 1u)) >> 16);
    u = __float_as_uint(v.z); o.z = (unsigned short)((u + 0x7fffu + ((u >> 16) & 1u)) >> 16);
    u = __float_as_uint(v.w); o.w = (unsigned short)((u + 0x7fffu + ((u >> 16) & 1u)) >> 16);
    ((ushort4*)h16)[i] = o;
}

// ---- K0a: bucket histogram (LDS-privatized) + zero edge part of out ----
__global__ void hist_zero_kernel(const int* __restrict__ dst,
                                 int* __restrict__ counts,
                                 float* __restrict__ out_edge) {
    __shared__ int lcnt[NB];
    for (int i = threadIdx.x; i < NB; i += blockDim.x) lcnt[i] = 0;
    __syncthreads();
    int base = blockIdx.x * H_EPB;
    int end  = base + H_EPB; if (end > N_EDGES) end = N_EDGES;
    for (int i = base + threadIdx.x; i < end; i += blockDim.x) {
        __hip_atomic_fetch_add(&lcnt[dst[i] >> BSH], 1,
                               __ATOMIC_RELAXED, __HIP_MEMORY_SCOPE_WORKGROUP);
        out_edge[i] = 0.0f;
    }
    __syncthreads();
    for (int i = threadIdx.x; i < NB; i += blockDim.x) {
        int c = lcnt[i];
        if (c) atomicAdd(&counts[i], c);
    }
}

// ---- K0b: scan bucket counts -> offs/curs; init bflag, node_offs tail ----
__global__ void scan_kernel(const int* __restrict__ counts,
                            int* __restrict__ offs,
                            int* __restrict__ curs,
                            int* __restrict__ bflag,
                            int* __restrict__ node_offs) {
    __shared__ int sb[NBP];
    int t = threadIdx.x;
    int c = (t < NB) ? counts[t] : 0;
    sb[t] = c;
    __syncthreads();
    for (int off = 1; off < NBP; off <<= 1) {
        int v = 0;
        if (t >= off) v = sb[t - off];
        __syncthreads();
        sb[t] += v;
        __syncthreads();
    }
    if (t < NB) {
        offs[t] = sb[t] - c;
        curs[t] = sb[t] - c;
        bflag[t] = 0;
    }
    if (t == NBP - 1) offs[NB] = sb[t];
    if (t == 0) node_offs[N_NODES] = N_EDGES;
}

// ---- K1: chunk-local LDS sort by bucket, burst-copy to global bins ----
__global__ void __launch_bounds__(512)
bucket_scatter_kernel(const int* __restrict__ src,
                      const int* __restrict__ dst,
                      const float* __restrict__ e,
                      int* __restrict__ curs,
                      uint2* __restrict__ recs) {
    __shared__ uint2          stage[K1_CH];       // 32 KB
    __shared__ unsigned short bkt16[K1_CH];       // 8 KB
    __shared__ int hist[NB], ebuf[NB], cur[NB], gbase[NB];
    __shared__ int sb[NBP];

    const int t    = threadIdx.x;
    const int base = blockIdx.x * K1_CH;
    int chcnt = N_EDGES - base; if (chcnt > K1_CH) chcnt = K1_CH;

    int dv[8];                                    // register-cached dst
    for (int i = t; i < NB; i += 512) hist[i] = 0;
    __syncthreads();
#pragma unroll
    for (int j = 0; j < 8; ++j) {
        int i = j * 512 + t;
        if (i < chcnt) {
            dv[j] = dst[base + i];
            __hip_atomic_fetch_add(&hist[dv[j] >> BSH], 1,
                                   __ATOMIC_RELAXED, __HIP_MEMORY_SCOPE_WORKGROUP);
        } else dv[j] = -1;
    }
    __syncthreads();
    int c = (t < NB) ? hist[t] : 0;
    sb[t] = c;
    __syncthreads();
    for (int off = 1; off < NBP; off <<= 1) {
        int v = 0;
        if (t >= off) v = sb[t - off];
        __syncthreads();
        sb[t] += v;
        __syncthreads();
    }
    if (t < NB) {
        ebuf[t] = sb[t] - c;
        cur[t]  = 0;
        gbase[t] = c ? atomicAdd(&curs[t], c) : 0;
    }
    __syncthreads();
#pragma unroll
    for (int j = 0; j < 8; ++j) {
        int i = j * 512 + t;
        if (dv[j] >= 0) {
            int gi = base + i;
            int b  = dv[j] >> BSH;
            int p  = ebuf[b] + __hip_atomic_fetch_add(&cur[b], 1,
                            __ATOMIC_RELAXED, __HIP_MEMORY_SCOPE_WORKGROUP);
            unsigned pk = (unsigned)src[gi] | ((unsigned)(dv[j] & (BN - 1)) << 17);
            stage[p] = make_uint2(pk, __float_as_uint(e[gi]));
            bkt16[p] = (unsigned short)b;
        }
    }
    __syncthreads();
    for (int i = t; i < chcnt; i += 512) {
        int b = bkt16[i];
        recs[gbase[b] + (i - ebuf[b])] = stage[i];
    }
}

// ---- K2: per-bucket node-level sort (in LDS, in place) + node_offs ----
__global__ void __launch_bounds__(512)
node_sort_kernel(const int* __restrict__ offs,
                 uint2* __restrict__ recs,
                 int* __restrict__ bflag,
                 int* __restrict__ node_offs) {
    __shared__ uint2 buf[K2_CAP];                 // 80 KB
    __shared__ int hist[BN], ebuf[BN], cur[BN];

    const int b  = blockIdx.x;
    const int t  = threadIdx.x;
    const int lo = offs[b];
    const int cnt = offs[b + 1] - lo;

    if (cnt > K2_CAP) {
        if (t == 0) bflag[b] = 1;
        if (t < BN) {
            int g = (b << BSH) + t;
            if (g < N_NODES) node_offs[g] = lo;
        }
        return;
    }

    for (int i = t; i < cnt; i += 512) buf[i] = recs[lo + i];
    if (t < BN) hist[t] = 0;
    __syncthreads();
    for (int i = t; i < cnt; i += 512) {
        int dl = buf[i].x >> 17;
        __hip_atomic_fetch_add(&hist[dl], 1,
                               __ATOMIC_RELAXED, __HIP_MEMORY_SCOPE_WORKGROUP);
    }
    __syncthreads();
    int c = 0;
    if (t < BN) { c = hist[t]; ebuf[t] = c; }
    __syncthreads();
    for (int off = 1; off < BN; off <<= 1) {
        int v = 0;
        if (t < BN && t >= off) v = ebuf[t - off];
        __syncthreads();
        if (t < BN) ebuf[t] += v;
        __syncthreads();
    }
    if (t < BN) {
        int exc = ebuf[t] - c;
        ebuf[t] = exc;
        cur[t]  = 0;
        int g = (b << BSH) + t;
        if (g < N_NODES) node_offs[g] = lo + exc;
    }
    __syncthreads();
    for (int i = t; i < cnt; i += 512) {
        uint2 r = buf[i];
        int dl = r.x >> 17;
        int p  = lo + ebuf[dl] + __hip_atomic_fetch_add(&cur[dl], 1,
                        __ATOMIC_RELAXED, __HIP_MEMORY_SCOPE_WORKGROUP);
        recs[p] = r;
    }
}

// ---- K3 (bf16 h): wave = node; 8 groups x 8 lanes; uint4 row loads ----
// group g handles recs lo+g, lo+g+8, ... (unroll 4); lane sub owns
// features [sub*8, sub*8+8) as one uint4 of 8 bf16.
__global__ void __launch_bounds__(512)
gather_bf16_kernel(const float* __restrict__ h,
                   const unsigned short* __restrict__ h16,
                   const int* __restrict__ offs,
                   const int* __restrict__ node_offs,
                   const int* __restrict__ bflag,
                   const uint2* __restrict__ recs,
                   float* __restrict__ out) {
    const int wid = threadIdx.x >> 6;
    const int n   = blockIdx.x * 8 + wid;
    if (n >= N_NODES) return;
    const int lane = threadIdx.x & 63;
    const int g    = lane >> 3;        // 0..7
    const int sub  = lane & 7;         // 0..7
    const int b    = n >> BSH;

    const uint4* __restrict__ hv = (const uint4*)h16;   // 8 uint4 per row

    float a0=0.f,a1=0.f,a2=0.f,a3=0.f,a4=0.f,a5=0.f,a6=0.f,a7=0.f;

#define ACC_REC(r)                                                          \
    {                                                                       \
        uint4 v = hv[(r.x & SRC_MASK) * 8 + sub];                           \
        float w = __uint_as_float(r.y);                                     \
        a0 += __uint_as_float(v.x << 16) * w;                               \
        a1 += __uint_as_float(v.x & 0xFFFF0000u) * w;                       \
        a2 += __uint_as_float(v.y << 16) * w;                               \
        a3 += __uint_as_float(v.y & 0xFFFF0000u) * w;                       \
        a4 += __uint_as_float(v.z << 16) * w;                               \
        a5 += __uint_as_float(v.z & 0xFFFF0000u) * w;                       \
        a6 += __uint_as_float(v.w << 16) * w;                               \
        a7 += __uint_as_float(v.w & 0xFFFF0000u) * w;                       \
    }

    if (!bflag[b]) {
        const int lo = node_offs[n], hi = node_offs[n + 1];
        int kk = lo + g;
        while (kk < hi) {
            uint2 r0 = recs[kk];                                  // kk < hi
            uint2 r1 = (kk +  8 < hi) ? recs[kk +  8] : make_uint2(0u, 0u);
            uint2 r2 = (kk + 16 < hi) ? recs[kk + 16] : make_uint2(0u, 0u);
            uint2 r3 = (kk + 24 < hi) ? recs[kk + 24] : make_uint2(0u, 0u);
            ACC_REC(r0); ACC_REC(r1); ACC_REC(r2); ACC_REC(r3);
            kk += 32;
        }
    } else {                                      // unsorted bucket: scan-match
        const int lo = offs[b], hi = offs[b + 1];
        const unsigned dl = (unsigned)(n & (BN - 1));
        for (int k = lo + g; k < hi; k += 8) {
            uint2 r = recs[k];
            if ((r.x >> 17) == dl) ACC_REC(r);
        }
    }
#undef ACC_REC

    // reduce across the 8 edge-groups (lanes with same sub)
    for (int m = 8; m <= 32; m <<= 1) {
        a0 += __shfl_xor(a0, m); a1 += __shfl_xor(a1, m);
        a2 += __shfl_xor(a2, m); a3 += __shfl_xor(a3, m);
        a4 += __shfl_xor(a4, m); a5 += __shfl_xor(a5, m);
        a6 += __shfl_xor(a6, m); a7 += __shfl_xor(a7, m);
    }

    if (g == 0) {
        const float4* __restrict__ h4 = (const float4*)h;
        const int o = n * 16 + sub * 2;
        float4 p = h4[o], q = h4[o + 1];
        float4 r0, r1;
        r0.x = a0 - GAMMA * p.x; r0.y = a1 - GAMMA * p.y;
        r0.z = a2 - GAMMA * p.z; r0.w = a3 - GAMMA * p.w;
        r1.x = a4 - GAMMA * q.x; r1.y = a5 - GAMMA * q.y;
        r1.z = a6 - GAMMA * q.z; r1.w = a7 - GAMMA * q.w;
        ((float4*)out)[o]     = r0;
        ((float4*)out)[o + 1] = r1;
    }
}

// ---- K3 (f32 h fallback): 4 groups x 16 lanes, float4 gather ----
__global__ void __launch_bounds__(512)
gather_kernel(const float* __restrict__ h,
              const int* __restrict__ offs,
              const int* __restrict__ node_offs,
              const int* __restrict__ bflag,
              const uint2* __restrict__ recs,
              float* __restrict__ out) {
    const int wid = threadIdx.x >> 6;
    const int n   = blockIdx.x * 8 + wid;
    if (n >= N_NODES) return;
    const int lane = threadIdx.x & 63;
    const int g    = lane >> 4;
    const int sub  = lane & 15;
    const int b    = n >> BSH;

    const float4* __restrict__ h4 = (const float4*)h;
    float ax = 0.f, ay = 0.f, az = 0.f, aw = 0.f;

    if (!bflag[b]) {
        const int lo = node_offs[n], hi = node_offs[n + 1];
        int kk = lo + g;
        while (kk < hi) {
            uint2 c0 = recs[kk];
            uint2 c1 = (kk + 4 < hi) ? recs[kk + 4] : make_uint2(0u, 0u);
            kk += 8;
            float4 v0 = h4[(c0.x & SRC_MASK) * 16 + sub];
            float4 v1 = h4[(c1.x & SRC_MASK) * 16 + sub];
            float  w0 = __uint_as_float(c0.y);
            float  w1 = __uint_as_float(c1.y);
            ax += v0.x * w0 + v1.x * w1;
            ay += v0.y * w0 + v1.y * w1;
            az += v0.z * w0 + v1.z * w1;
            aw += v0.w * w0 + v1.w * w1;
        }
    } else {
        const int lo = offs[b], hi = offs[b + 1];
        const unsigned dl = (unsigned)(n & (BN - 1));
        for (int k = lo + g; k < hi; k += 4) {
            uint2 r = recs[k];
            if ((r.x >> 17) == dl) {
                float4 v = h4[(r.x & SRC_MASK) * 16 + sub];
                float  w = __uint_as_float(r.y);
                ax += v.x * w; ay += v.y * w; az += v.z * w; aw += v.w * w;
            }
        }
    }

    for (int m = 16; m <= 32; m <<= 1) {
        ax += __shfl_xor(ax, m);
        ay += __shfl_xor(ay, m);
        az += __shfl_xor(az, m);
        aw += __shfl_xor(aw, m);
    }

    if (g == 0) {
        const int o = n * 16 + sub;
        float4 h0 = h4[o];
        float4 r;
        r.x = ax - GAMMA * h0.x;
        r.y = ay - GAMMA * h0.y;
        r.z = az - GAMMA * h0.z;
        r.w = aw - GAMMA * h0.w;
        ((float4*)out)[o] = r;
    }
}

// ---------------- fallback atomic path (if ws too small) ----------------
__global__ void init_out_kernel(const float* __restrict__ x,
                                float* __restrict__ out,
                                int nd, int total) {
    int i = blockIdx.x * blockDim.x + threadIdx.x;
    if (i < nd)         out[i] = -GAMMA * x[i];
    else if (i < total) out[i] = 0.0f;
}

__global__ void edge_scatter_kernel(const float* __restrict__ h,
                                    const float* __restrict__ e,
                                    const int* __restrict__ src,
                                    const int* __restrict__ dst,
                                    float* __restrict__ out) {
    long long idx = (long long)blockIdx.x * blockDim.x + threadIdx.x;
    int edge = (int)(idx >> 6);
    int d    = (int)(idx & 63);
    if (edge >= N_EDGES) return;
    atomicAdd(&out[dst[edge] * D_FEAT + d], h[src[edge] * D_FEAT + d] * e[edge]);
}

// ---------------- launch ----------------
extern "C" void kernel_launch(void* const* d_in, const int* in_sizes, int n_in,
                              void* d_out, int out_size, void* d_ws, size_t ws_size,
                              hipStream_t stream) {
    const float* x   = (const float*)d_in[1];
    const int*   src = (const int*)d_in[2];
    const int*   dst = (const int*)d_in[3];
    float*       out = (float*)d_out;

    const int nd = N_NODES * D_FEAT;

    // ws: counts[NB] | offs[NB+1] | curs[NB] | bflag[NB] | node_offs[N+1] |
    //     recs[E] (uint2) | h16[N*D] (bf16)
    size_t ints    = (size_t)NB * 3 + 1 + NB + (size_t)N_NODES + 1;
    size_t rec_off = (ints * 4 + 15) & ~(size_t)15;
    size_t needed      = rec_off + (size_t)N_EDGES * 8;
    size_t needed_bf16 = needed + (size_t)nd * 2;

    if (ws_size >= needed) {
        int*   counts    = (int*)d_ws;
        int*   offs      = counts + NB;
        int*   curs      = offs + NB + 1;
        int*   bflag     = curs + NB;
        int*   node_offs = bflag + NB;
        uint2* recs      = (uint2*)((char*)d_ws + rec_off);

        hipMemsetAsync(counts, 0, NB * sizeof(int), stream);
        bool use_bf16 = (ws_size >= needed_bf16);
        unsigned short* h16 = (unsigned short*)((char*)d_ws + needed);
        if (use_bf16)
            cvt_kernel<<<(nd / 4 + 255) / 256, 256, 0, stream>>>(x, h16);
        hist_zero_kernel<<<H_BLOCKS, 256, 0, stream>>>(dst, counts, out + nd);
        scan_kernel<<<1, NBP, 0, stream>>>(counts, offs, curs, bflag, node_offs);
        bucket_scatter_kernel<<<K1_BLOCKS, 512, 0, stream>>>(src, dst, x + nd, curs, recs);
        node_sort_kernel<<<NB, 512, 0, stream>>>(offs, recs, bflag, node_offs);
        if (use_bf16)
            gather_bf16_kernel<<<(N_NODES + 7) / 8, 512, 0, stream>>>(
                x, h16, offs, node_offs, bflag, recs, out);
        else
            gather_kernel<<<(N_NODES + 7) / 8, 512, 0, stream>>>(
                x, offs, node_offs, bflag, recs, out);
    } else {
        const int total = nd + N_EDGES;
        init_out_kernel<<<(total + 255) / 256, 256, 0, stream>>>(x, out, nd, total);
        long long threads = (long long)N_EDGES * 64;
        edge_scatter_kernel<<<(int)((threads + 255) / 256), 256, 0, stream>>>(
            x, x + nd, src, dst, out);
    }
}

// Round 7
// 183.391 us; speedup vs baseline: 11.6071x; 1.0013x over previous
//
#include <hip/hip_runtime.h>

#define N_NODES 100000
#define D_FEAT  64
#define N_EDGES 3200000
#define GAMMA   0.5f

#define BSH   8                                   // 256 nodes per bucket
#define BN    (1 << BSH)
#define NB    ((N_NODES + BN - 1) >> BSH)         // 391 buckets
#define NBP   512                                 // pow2 pad for scans

#define H_BLOCKS 1024
#define H_EPB    ((N_EDGES + H_BLOCKS - 1) / H_BLOCKS)   // 3125

#define CVT_V4     (N_NODES * D_FEAT / 4)         // 1,600,000 float4
#define CVT_BLOCKS ((CVT_V4 + 255) / 256)         // 6250

#define K1_CH    4096                             // edges per K1 block
#define K1_BLOCKS ((N_EDGES + K1_CH - 1) / K1_CH) // 782

#define KG_CAP   9472                             // bucket cap (avg 8184, +14 sigma)
#define KG_REG   19                               // ceil(KG_CAP/512)

#define SRC_MASK 0x1FFFFu                         // 17 bits for src

// ---- P0: fused [dst-bucket histogram + zero edge-out] | [h f32->bf16] ----
__global__ void pre_kernel(const float* __restrict__ h,
                           const int* __restrict__ dst,
                           unsigned short* __restrict__ h16,
                           int* __restrict__ counts,
                           float* __restrict__ out_edge) {
    __shared__ int lcnt[NB];
    const int bid = blockIdx.x;
    if (bid < H_BLOCKS) {
        for (int i = threadIdx.x; i < NB; i += 256) lcnt[i] = 0;
        __syncthreads();
        int base = bid * H_EPB;
        int end  = base + H_EPB; if (end > N_EDGES) end = N_EDGES;
        for (int i = base + threadIdx.x; i < end; i += 256) {
            __hip_atomic_fetch_add(&lcnt[dst[i] >> BSH], 1,
                                   __ATOMIC_RELAXED, __HIP_MEMORY_SCOPE_WORKGROUP);
            out_edge[i] = 0.0f;
        }
        __syncthreads();
        for (int i = threadIdx.x; i < NB; i += 256) {
            int c = lcnt[i];
            if (c) atomicAdd(&counts[i], c);
        }
    } else {
        int i = (bid - H_BLOCKS) * 256 + threadIdx.x;
        if (i < CVT_V4) {
            float4 v = ((const float4*)h)[i];
            ushort4 o;
            unsigned u;
            u = __float_as_uint(v.x); o.x = (unsigned short)((u + 0x7fffu + ((u >> 16) & 1u)) >> 16);
            u = __float_as_uint(v.y); o.y = (unsigned short)((u + 0x7fffu + ((u >> 16) & 1u)) >> 16);
            u = __float_as_uint(v.z); o.z = (unsigned short)((u + 0x7fffu + ((u >> 16) & 1u)) >> 16);
            u = __float_as_uint(v.w); o.w = (unsigned short)((u + 0x7fffu + ((u >> 16) & 1u)) >> 16);
            ((ushort4*)h16)[i] = o;
        }
    }
}

// ---- P1: scan bucket counts -> offs/curs ----
__global__ void scan_kernel(const int* __restrict__ counts,
                            int* __restrict__ offs,
                            int* __restrict__ curs) {
    __shared__ int sb[NBP];
    int t = threadIdx.x;
    int c = (t < NB) ? counts[t] : 0;
    sb[t] = c;
    __syncthreads();
    for (int off = 1; off < NBP; off <<= 1) {
        int v = 0;
        if (t >= off) v = sb[t - off];
        __syncthreads();
        sb[t] += v;
        __syncthreads();
    }
    if (t < NB) {
        offs[t] = sb[t] - c;
        curs[t] = sb[t] - c;
    }
    if (t == NBP - 1) offs[NB] = sb[t];
}

// ---- P2: chunk-local LDS sort by bucket, burst-copy to global bins ----
__global__ void __launch_bounds__(512)
bucket_scatter_kernel(const int* __restrict__ src,
                      const int* __restrict__ dst,
                      const float* __restrict__ e,
                      int* __restrict__ curs,
                      uint2* __restrict__ recs) {
    __shared__ uint2          stage[K1_CH];       // 32 KB
    __shared__ unsigned short bkt16[K1_CH];       // 8 KB
    __shared__ int hist[NB], ebuf[NB], cur[NB], gbase[NB];
    __shared__ int sb[NBP];

    const int t    = threadIdx.x;
    const int base = blockIdx.x * K1_CH;
    int chcnt = N_EDGES - base; if (chcnt > K1_CH) chcnt = K1_CH;

    int dv[8];                                    // register-cached dst
    for (int i = t; i < NB; i += 512) hist[i] = 0;
    __syncthreads();
#pragma unroll
    for (int j = 0; j < 8; ++j) {
        int i = j * 512 + t;
        if (i < chcnt) {
            dv[j] = dst[base + i];
            __hip_atomic_fetch_add(&hist[dv[j] >> BSH], 1,
                                   __ATOMIC_RELAXED, __HIP_MEMORY_SCOPE_WORKGROUP);
        } else dv[j] = -1;
    }
    __syncthreads();
    int c = (t < NB) ? hist[t] : 0;
    sb[t] = c;
    __syncthreads();
    for (int off = 1; off < NBP; off <<= 1) {
        int v = 0;
        if (t >= off) v = sb[t - off];
        __syncthreads();
        sb[t] += v;
        __syncthreads();
    }
    if (t < NB) {
        ebuf[t] = sb[t] - c;
        cur[t]  = 0;
        gbase[t] = c ? atomicAdd(&curs[t], c) : 0;
    }
    __syncthreads();
#pragma unroll
    for (int j = 0; j < 8; ++j) {
        int i = j * 512 + t;
        if (dv[j] >= 0) {
            int gi = base + i;
            int b  = dv[j] >> BSH;
            int p  = ebuf[b] + __hip_atomic_fetch_add(&cur[b], 1,
                            __ATOMIC_RELAXED, __HIP_MEMORY_SCOPE_WORKGROUP);
            unsigned pk = (unsigned)src[gi] | ((unsigned)(dv[j] & (BN - 1)) << 17);
            stage[p] = make_uint2(pk, __float_as_uint(e[gi]));
            bkt16[p] = (unsigned short)b;
        }
    }
    __syncthreads();
    for (int i = t; i < chcnt; i += 512) {
        int b = bkt16[i];
        recs[gbase[b] + (i - ebuf[b])] = stage[i];
    }
}

// ---- P3: fused [in-LDS node sort + gather]. One block per bucket. ----
__global__ void __launch_bounds__(512)
bucket_gather_kernel(const float* __restrict__ h,
                     const unsigned short* __restrict__ h16,
                     const int* __restrict__ offs,
                     const uint2* __restrict__ recs,
                     float* __restrict__ out) {
    __shared__ unsigned key[KG_CAP];              // 37888 B
    __shared__ float    wgt[KG_CAP];              // 37888 B
    __shared__ int hist[BN], cur[BN], ebuf[BN];   // 3 KB
    __shared__ int wsum[4];

    const int b    = blockIdx.x;
    const int t    = threadIdx.x;
    const int lane = t & 63;
    const int wid  = t >> 6;
    const int lo   = offs[b];
    const int cnt  = offs[b + 1] - lo;

    const uint4* __restrict__ hv = (const uint4*)h16;

    if (t < BN) { hist[t] = 0; cur[t] = 0; }
    __syncthreads();

    if (cnt <= KG_CAP) {
        // A: reg-cache recs + node histogram
        uint2 r[KG_REG];
#pragma unroll
        for (int j = 0; j < KG_REG; ++j) {
            int i = j * 512 + t;
            if (i < cnt) {
                r[j] = recs[lo + i];
                __hip_atomic_fetch_add(&hist[r[j].x >> 17], 1,
                                       __ATOMIC_RELAXED, __HIP_MEMORY_SCOPE_WORKGROUP);
            } else r[j].x = 0xFFFFFFFFu;
        }
        __syncthreads();
        // B: exclusive scan of 256 bins (wave shfl + cross-wave)
        int c_ = 0, v_ = 0;
        if (t < BN) {
            c_ = hist[t]; v_ = c_;
            for (int s = 1; s < 64; s <<= 1) {
                int u = __shfl_up(v_, s, 64);
                if (lane >= s) v_ += u;
            }
            if (lane == 63) wsum[wid] = v_;
        }
        __syncthreads();
        if (t < BN) {
            int pre = 0;
            for (int w2 = 0; w2 < wid; ++w2) pre += wsum[w2];
            ebuf[t] = pre + v_ - c_;
        }
        __syncthreads();
        // C: scatter into LDS, node-sorted
#pragma unroll
        for (int j = 0; j < KG_REG; ++j) {
            if (r[j].x != 0xFFFFFFFFu) {
                int dl = r[j].x >> 17;
                int p  = ebuf[dl] + __hip_atomic_fetch_add(&cur[dl], 1,
                                __ATOMIC_RELAXED, __HIP_MEMORY_SCOPE_WORKGROUP);
                key[p] = r[j].x;
                wgt[p] = __uint_as_float(r[j].y);
            }
        }
        __syncthreads();
        // D: gather. wave = 32 nodes; 8 groups x 8 lanes; uint4 h16 rows.
        const int g   = lane >> 3;
        const int sub = lane & 7;
        for (int i = 0; i < 32; ++i) {
            const int ln  = wid * 32 + i;
            const int nlo = ebuf[ln];
            const int nhi = nlo + hist[ln];
            float a0=0.f,a1=0.f,a2=0.f,a3=0.f,a4=0.f,a5=0.f,a6=0.f,a7=0.f;

#define ACC_KW(kk_, ww_)                                                    \
    {                                                                       \
        uint4 v = hv[((kk_) & SRC_MASK) * 8 + sub];                         \
        a0 += __uint_as_float(v.x << 16) * (ww_);                           \
        a1 += __uint_as_float(v.x & 0xFFFF0000u) * (ww_);                   \
        a2 += __uint_as_float(v.y << 16) * (ww_);                           \
        a3 += __uint_as_float(v.y & 0xFFFF0000u) * (ww_);                   \
        a4 += __uint_as_float(v.z << 16) * (ww_);                           \
        a5 += __uint_as_float(v.z & 0xFFFF0000u) * (ww_);                   \
        a6 += __uint_as_float(v.w << 16) * (ww_);                           \
        a7 += __uint_as_float(v.w & 0xFFFF0000u) * (ww_);                   \
    }
            int kk = nlo + g;
            while (kk < nhi) {
                unsigned k0 = key[kk];
                float    w0 = wgt[kk];
                bool m1 = kk +  8 < nhi;
                bool m2 = kk + 16 < nhi;
                bool m3 = kk + 24 < nhi;
                unsigned k1 = m1 ? key[kk +  8] : 0u;  float w1 = m1 ? wgt[kk +  8] : 0.f;
                unsigned k2 = m2 ? key[kk + 16] : 0u;  float w2 = m2 ? wgt[kk + 16] : 0.f;
                unsigned k3 = m3 ? key[kk + 24] : 0u;  float w3 = m3 ? wgt[kk + 24] : 0.f;
                ACC_KW(k0, w0); ACC_KW(k1, w1); ACC_KW(k2, w2); ACC_KW(k3, w3);
                kk += 32;
            }
#undef ACC_KW
            for (int m = 8; m <= 32; m <<= 1) {
                a0 += __shfl_xor(a0, m); a1 += __shfl_xor(a1, m);
                a2 += __shfl_xor(a2, m); a3 += __shfl_xor(a3, m);
                a4 += __shfl_xor(a4, m); a5 += __shfl_xor(a5, m);
                a6 += __shfl_xor(a6, m); a7 += __shfl_xor(a7, m);
            }
            const int n = (b << BSH) + ln;
            if (g == 0 && n < N_NODES) {
                const float4* __restrict__ h4 = (const float4*)h;
                const int o = n * 16 + sub * 2;
                float4 p = h4[o], q = h4[o + 1];
                float4 r0, r1;
                r0.x = a0 - GAMMA * p.x; r0.y = a1 - GAMMA * p.y;
                r0.z = a2 - GAMMA * p.z; r0.w = a3 - GAMMA * p.w;
                r1.x = a4 - GAMMA * q.x; r1.y = a5 - GAMMA * q.y;
                r1.z = a6 - GAMMA * q.z; r1.w = a7 - GAMMA * q.w;
                ((float4*)out)[o]     = r0;
                ((float4*)out)[o + 1] = r1;
            }
        }
    } else {
        // slow fallback (never expected): scan-match from global recs
        const int d = lane;
        for (int i = 0; i < 32; ++i) {
            const int ln = wid * 32 + i;
            const int n  = (b << BSH) + ln;
            if (n >= N_NODES) continue;
            float acc = 0.f;
            for (int k = 0; k < cnt; ++k) {
                uint2 rr = recs[lo + k];
                if ((int)(rr.x >> 17) == ln) {
                    unsigned hb = h16[(rr.x & SRC_MASK) * D_FEAT + d];
                    acc += __uint_as_float(hb << 16) * __uint_as_float(rr.y);
                }
            }
            int o = n * D_FEAT + d;
            out[o] = acc - GAMMA * h[o];
        }
    }
}

// ---------------- fallback atomic path (if ws too small) ----------------
__global__ void init_out_kernel(const float* __restrict__ x,
                                float* __restrict__ out,
                                int nd, int total) {
    int i = blockIdx.x * blockDim.x + threadIdx.x;
    if (i < nd)         out[i] = -GAMMA * x[i];
    else if (i < total) out[i] = 0.0f;
}

__global__ void edge_scatter_kernel(const float* __restrict__ h,
                                    const float* __restrict__ e,
                                    const int* __restrict__ src,
                                    const int* __restrict__ dst,
                                    float* __restrict__ out) {
    long long idx = (long long)blockIdx.x * blockDim.x + threadIdx.x;
    int edge = (int)(idx >> 6);
    int d    = (int)(idx & 63);
    if (edge >= N_EDGES) return;
    atomicAdd(&out[dst[edge] * D_FEAT + d], h[src[edge] * D_FEAT + d] * e[edge]);
}

// ---------------- launch ----------------
extern "C" void kernel_launch(void* const* d_in, const int* in_sizes, int n_in,
                              void* d_out, int out_size, void* d_ws, size_t ws_size,
                              hipStream_t stream) {
    const float* x   = (const float*)d_in[1];
    const int*   src = (const int*)d_in[2];
    const int*   dst = (const int*)d_in[3];
    float*       out = (float*)d_out;

    const int nd = N_NODES * D_FEAT;

    // ws: counts[NB] | offs[NB+1] | curs[NB] | pad | recs[E] (uint2) | h16[nd]
    size_t ints    = (size_t)NB * 3 + 1;
    size_t rec_off = (ints * 4 + 15) & ~(size_t)15;
    size_t h16_off = rec_off + (size_t)N_EDGES * 8;
    size_t needed  = h16_off + (size_t)nd * 2;

    if (ws_size >= needed) {
        int*   counts = (int*)d_ws;
        int*   offs   = counts + NB;
        int*   curs   = offs + NB + 1;
        uint2* recs   = (uint2*)((char*)d_ws + rec_off);
        unsigned short* h16 = (unsigned short*)((char*)d_ws + h16_off);

        hipMemsetAsync(counts, 0, NB * sizeof(int), stream);
        pre_kernel<<<H_BLOCKS + CVT_BLOCKS, 256, 0, stream>>>(x, dst, h16, counts, out + nd);
        scan_kernel<<<1, NBP, 0, stream>>>(counts, offs, curs);
        bucket_scatter_kernel<<<K1_BLOCKS, 512, 0, stream>>>(src, dst, x + nd, curs, recs);
        bucket_gather_kernel<<<NB, 512, 0, stream>>>(x, h16, offs, recs, out);
    } else {
        const int total = nd + N_EDGES;
        init_out_kernel<<<(total + 255) / 256, 256, 0, stream>>>(x, out, nd, total);
        long long threads = (long long)N_EDGES * 64;
        edge_scatter_kernel<<<(int)((threads + 255) / 256), 256, 0, stream>>>(
            x, x + nd, src, dst, out);
    }
}